// Round 1
// baseline (209.693 us; speedup 1.0000x reference)
//
#include <hip/hip_runtime.h>

// B=8, S=256, T=32, D=512, He=512, Fd=128
// flat row r = b*S+s for E/L1/F ([2048,512]); r = b*T+t for O/O2/O3 ([256,512])

typedef __attribute__((ext_vector_type(8))) short bf16x8;
typedef __attribute__((ext_vector_type(4))) float f32x4;

__device__ __forceinline__ unsigned short f2bf(float x) {
    union { float f; unsigned u; } v; v.f = x;
    unsigned r = v.u + 0x7fffu + ((v.u >> 16) & 1u);
    return (unsigned short)(r >> 16);
}

// ---- fused prep: 0..1407 fp32->bf16 cvt (E,Z,O); 1408..2239 W transpose;
//      2240..2495 zero sum/csum accumulators (needed every replay for atomics) ----
__global__ __launch_bounds__(256) void prep_k(
    const float* __restrict__ E, const float* __restrict__ Z, const float* __restrict__ O,
    const float* __restrict__ W1, const float* __restrict__ W2,
    const float* __restrict__ W3, const float* __restrict__ W4,
    unsigned short* __restrict__ Ebf, unsigned short* __restrict__ Zbf,
    unsigned short* __restrict__ Obf,
    unsigned short* __restrict__ W1T, unsigned short* __restrict__ W2T,
    unsigned short* __restrict__ W3T, unsigned short* __restrict__ W4T,
    float* __restrict__ sum, float* __restrict__ csum)
{
    int bid = blockIdx.x;
    if (bid >= 2240) {
        // zero 2 x 131072 floats (sum, csum): 256 blocks x 256 thr x 4 floats
        int idx = (bid - 2240) * 1024 + threadIdx.x * 4;
        float* p = (idx < 131072) ? (sum + idx) : (csum + (idx - 131072));
        *(f32x4*)p = f32x4{0.f, 0.f, 0.f, 0.f};
        return;
    }
    if (bid < 1408) {
        const float* src; unsigned short* dst; int base;
        if (bid < 1024)      { src = E; dst = Ebf; base = bid; }
        else if (bid < 1280) { src = Z; dst = Zbf; base = bid - 1024; }
        else                 { src = O; dst = Obf; base = bid - 1280; }
        int i = base * 1024 + threadIdx.x * 4;
        float4 v = *(const float4*)(src + i);
        ushort4 r;
        r.x = f2bf(v.x); r.y = f2bf(v.y); r.z = f2bf(v.z); r.w = f2bf(v.w);
        *(ushort4*)(dst + i) = r;
        return;
    }
    int tb = bid - 1408;
    const float* W; unsigned short* WT; int K;
    if (tb < 256)      {            W = W1; WT = W1T; K = 512; }
    else if (tb < 512) { tb -= 256; W = W2; WT = W2T; K = 512; }
    else if (tb < 576) { tb -= 512; W = W3; WT = W3T; K = 128; }
    else               { tb -= 576; W = W4; WT = W4T; K = 512; }
    int n0 = (tb & 15) * 32;
    int k0 = (tb >> 4) * 32;
    __shared__ float tile[32][33];
    int tx = threadIdx.x & 31, ty = threadIdx.x >> 5;  // 32 x 8
    #pragma unroll
    for (int i = 0; i < 32; i += 8)
        tile[ty + i][tx] = W[(k0 + ty + i) * 512 + n0 + tx];
    __syncthreads();
    #pragma unroll
    for (int i = 0; i < 32; i += 8)
        WT[(n0 + ty + i) * K + k0 + tx] = f2bf(tile[tx][ty + i]);
}

// ---- merged MFMA GEMM: C = tanh(A @ BT^T + bias), N=512, BK=64, packed 1D grid ----
// ids 0..255: L1 (M=2048,K=512) | 256..511: F (M=2048,K=128)
// 512..543: O2 (M=256,K=512)    | 544..575: O3 (M=256,K=512)
__global__ __launch_bounds__(256) void gemm_all_k(
    const unsigned short* __restrict__ Ebf, const unsigned short* __restrict__ Zbf,
    const unsigned short* __restrict__ Obf,
    const unsigned short* __restrict__ W1T, const unsigned short* __restrict__ W3T,
    const unsigned short* __restrict__ W2T, const unsigned short* __restrict__ W4T,
    const float* __restrict__ b1, const float* __restrict__ b3,
    const float* __restrict__ b2, const float* __restrict__ b4,
    float* __restrict__ L1, float* __restrict__ F,
    float* __restrict__ O2, float* __restrict__ O3)
{
    int id = blockIdx.x;
    const unsigned short* A; const unsigned short* BT; const float* bias; float* C;
    int K;
    if (id < 256)      {             A = Ebf; BT = W1T; bias = b1; C = L1; K = 512; }
    else if (id < 512) { id -= 256;  A = Zbf; BT = W3T; bias = b3; C = F;  K = 128; }
    else if (id < 544) { id -= 512;  A = Obf; BT = W2T; bias = b2; C = O2; K = 512; }
    else               { id -= 544;  A = Obf; BT = W4T; bias = b4; C = O3; K = 512; }
    int m0 = (id >> 3) * 64;
    int n0 = (id & 7) * 64;

    // stride 72 shorts (144B): 16B-aligned for b128, 2-way conflicts max (free)
    __shared__ unsigned short As[64 * 72];
    __shared__ unsigned short Bs[64 * 72];

    int tid  = threadIdx.x;
    int wave = tid >> 6;
    int lane = tid & 63;
    int lm   = lane & 15;
    int lq   = lane >> 4;

    int srow = tid >> 2;          // 0..63
    int scol = (tid & 3) * 16;    // 0,16,32,48 (shorts)

    f32x4 acc[4];
    #pragma unroll
    for (int c = 0; c < 4; ++c) acc[c] = f32x4{0.f, 0.f, 0.f, 0.f};

    for (int k0 = 0; k0 < K; k0 += 64) {
        __syncthreads();
        const unsigned short* Ap = &A[(m0 + srow) * K + k0 + scol];
        const unsigned short* Bp = &BT[(n0 + srow) * K + k0 + scol];
        *(uint4*)(&As[srow * 72 + scol])     = *(const uint4*)(Ap);
        *(uint4*)(&As[srow * 72 + scol + 8]) = *(const uint4*)(Ap + 8);
        *(uint4*)(&Bs[srow * 72 + scol])     = *(const uint4*)(Bp);
        *(uint4*)(&Bs[srow * 72 + scol + 8]) = *(const uint4*)(Bp + 8);
        __syncthreads();
        #pragma unroll
        for (int ks = 0; ks < 2; ++ks) {
            bf16x8 af = *(const bf16x8*)(&As[(wave * 16 + lm) * 72 + ks * 32 + lq * 8]);
            #pragma unroll
            for (int c = 0; c < 4; ++c) {
                bf16x8 bfr = *(const bf16x8*)(&Bs[(c * 16 + lm) * 72 + ks * 32 + lq * 8]);
                acc[c] = __builtin_amdgcn_mfma_f32_16x16x32_bf16(af, bfr, acc[c], 0, 0, 0);
            }
        }
    }

    // C/D layout: col = lane&15, row = (lane>>4)*4 + r  (verified round 1)
    #pragma unroll
    for (int c = 0; c < 4; ++c) {
        int col = n0 + c * 16 + lm;
        float bv = bias[col];
        #pragma unroll
        for (int r = 0; r < 4; ++r) {
            int row = m0 + wave * 16 + lq * 4 + r;
            float x = acc[c][r] + bv;
            x = fminf(fmaxf(x, -15.f), 15.f);
            float t = __expf(2.0f * x);
            C[row * 512 + col] = (t - 1.0f) / (t + 1.0f);
        }
    }
}

// ---- attention stage A: accumulate softmax denominators via device atomics ----
// sum/csum: [256 (bt), 512 (d)] fp32, zeroed by prep_k
__global__ __launch_bounds__(256) void attn_partial_k(
    const float* __restrict__ L1, const float* __restrict__ F,
    const float* __restrict__ O2, const float* __restrict__ O3,
    const float* __restrict__ Enc,
    float* __restrict__ sum, float* __restrict__ csum)
{
    int b  = blockIdx.x >> 4;
    int sc = blockIdx.x & 15;
    int tc = blockIdx.y;                  // 0..3 -> 8 t each
    int d  = blockIdx.z * 256 + threadIdx.x;

    float c2[8], c3[8], s_[8], cs[8];
    #pragma unroll
    for (int i = 0; i < 8; ++i) {
        int bt = b * 32 + tc * 8 + i;
        c2[i] = O2[bt * 512 + d];
        c3[i] = O3[bt * 512 + d];
        s_[i] = 0.f; cs[i] = 0.f;
    }

    int s0 = sc * 16;
    const float* L1b = L1  + (b * 256 + s0) * 512 + d;
    const float* Fb  = F   + (b * 256 + s0) * 512 + d;
    const float* Eb  = Enc + (b * 256 + s0) * 512 + d;

    #pragma unroll 2
    for (int s = 0; s < 16; ++s) {
        float l1 = L1b[s * 512];
        float f  = Fb[s * 512];
        float eh = Eb[s * 512];
        #pragma unroll
        for (int i = 0; i < 8; ++i) {
            float e = __expf(l1 * c2[i] + f * c3[i]);
            s_[i]  += e;
            cs[i]  += e * eh;
        }
    }

    #pragma unroll
    for (int i = 0; i < 8; ++i) {
        int idx = (b * 32 + tc * 8 + i) * 512 + d;
        atomicAdd(&sum[idx],  s_[i]);
        atomicAdd(&csum[idx], cs[i]);
    }
}

// ---- attention stage B: recompute exp, stream 134 MB gamma; also emits out0 ----
// grid (8 b, 32 s-chunks of 8, 8 t-chunks of 4) = 2048 blocks (8/CU, vs 256 before)
// b fastest-varying -> all blocks of batch b on XCD b (L1/F slice L2-resident)
__global__ __launch_bounds__(256) void attn_write_k(
    const float* __restrict__ L1, const float* __restrict__ F,
    const float* __restrict__ O2, const float* __restrict__ O3,
    const float* __restrict__ sum, const float* __restrict__ csum,
    const float* __restrict__ Out,
    float* __restrict__ out0, float* __restrict__ attn)
{
    int b     = blockIdx.x;
    int sbase = blockIdx.y * 8 + (threadIdx.x >> 7) * 4;
    int tz    = blockIdx.z;               // 0..7 -> 4 t each
    int d4    = (threadIdx.x & 127) * 4;

    f32x4 l1[4], f[4];
    #pragma unroll
    for (int j = 0; j < 4; ++j) {
        l1[j] = *(const f32x4*)(L1 + (b * 256 + sbase + j) * 512 + d4);
        f[j]  = *(const f32x4*)(F  + (b * 256 + sbase + j) * 512 + d4);
    }

    for (int ti = 0; ti < 4; ++ti) {
        int bt = b * 32 + tz * 4 + ti;
        f32x4 c2 = *(const f32x4*)(O2  + bt * 512 + d4);
        f32x4 c3 = *(const f32x4*)(O3  + bt * 512 + d4);
        f32x4 sm = *(const f32x4*)(sum + bt * 512 + d4);
        f32x4 iv;
        iv[0] = 1.0f / sm[0]; iv[1] = 1.0f / sm[1];
        iv[2] = 1.0f / sm[2]; iv[3] = 1.0f / sm[3];
        #pragma unroll
        for (int j = 0; j < 4; ++j) {
            f32x4 g;
            g[0] = __expf(l1[j][0] * c2[0] + f[j][0] * c3[0]) * iv[0];
            g[1] = __expf(l1[j][1] * c2[1] + f[j][1] * c3[1]) * iv[1];
            g[2] = __expf(l1[j][2] * c2[2] + f[j][2] * c3[2]) * iv[2];
            g[3] = __expf(l1[j][3] * c2[3] + f[j][3] * c3[3]) * iv[3];
            __builtin_nontemporal_store(
                g, (f32x4*)(attn + ((size_t)(bt * 256 + sbase + j)) * 512 + d4));
        }
        // out0 concat rows: one s-chunk's blocks (y==0), lower half-threads cover all d
        if (blockIdx.y == 0 && threadIdx.x < 128) {
            f32x4 ov = *(const f32x4*)(Out  + bt * 512 + d4);
            f32x4 cv = *(const f32x4*)(csum + bt * 512 + d4);
            f32x4 cx;
            cx[0] = cv[0] * iv[0]; cx[1] = cv[1] * iv[1];
            cx[2] = cv[2] * iv[2]; cx[3] = cv[3] * iv[3];
            *(f32x4*)(out0 + bt * 1024 + d4)       = ov;
            *(f32x4*)(out0 + bt * 1024 + 512 + d4) = cx;
        }
    }
}

extern "C" void kernel_launch(void* const* d_in, const int* in_sizes, int n_in,
                              void* d_out, int out_size, void* d_ws, size_t ws_size,
                              hipStream_t stream)
{
    const float* Out = (const float*)d_in[0];
    const float* Enc = (const float*)d_in[1];
    const float* Z   = (const float*)d_in[2];
    const float* W1  = (const float*)d_in[3];
    const float* b1  = (const float*)d_in[4];
    const float* W2  = (const float*)d_in[5];
    const float* b2  = (const float*)d_in[6];
    const float* W3  = (const float*)d_in[7];
    const float* b3  = (const float*)d_in[8];
    const float* W4  = (const float*)d_in[9];
    const float* b4  = (const float*)d_in[10];

    char* ws = (char*)d_ws;
    size_t off = 0;
    auto alloc = [&](size_t n) -> char* {
        char* p = ws + off; off += (n + 255) & ~(size_t)255; return p;
    };
    unsigned short* Ebf = (unsigned short*)alloc(1048576 * 2);
    unsigned short* Zbf = (unsigned short*)alloc(262144 * 2);
    unsigned short* Obf = (unsigned short*)alloc(131072 * 2);
    unsigned short* W1T = (unsigned short*)alloc(262144 * 2);
    unsigned short* W2T = (unsigned short*)alloc(262144 * 2);
    unsigned short* W3T = (unsigned short*)alloc(65536 * 2);
    unsigned short* W4T = (unsigned short*)alloc(262144 * 2);
    float* L1   = (float*)alloc(1048576 * 4);
    float* F    = (float*)alloc(1048576 * 4);
    float* O2   = (float*)alloc(131072 * 4);
    float* O3   = (float*)alloc(131072 * 4);
    float* sum  = (float*)alloc(131072 * 4);
    float* csum = (float*)alloc(131072 * 4);

    float* out0 = (float*)d_out;            // [8,32,1024]
    float* attn = out0 + 262144;            // [8,32,256,512]

    hipLaunchKernelGGL(prep_k, dim3(2496), dim3(256), 0, stream,
                       Enc, Z, Out, W1, W2, W3, W4,
                       Ebf, Zbf, Obf, W1T, W2T, W3T, W4T, sum, csum);
    hipLaunchKernelGGL(gemm_all_k, dim3(576), dim3(256), 0, stream,
                       Ebf, Zbf, Obf, W1T, W3T, W2T, W4T,
                       b1, b3, b2, b4, L1, F, O2, O3);
    hipLaunchKernelGGL(attn_partial_k, dim3(128, 4, 2), dim3(256), 0, stream,
                       L1, F, O2, O3, Enc, sum, csum);
    hipLaunchKernelGGL(attn_write_k, dim3(8, 32, 8), dim3(256), 0, stream,
                       L1, F, O2, O3, sum, csum, Out, out0, attn);
}

// Round 2
// 201.907 us; speedup vs baseline: 1.0386x; 1.0386x over previous
//
#include <hip/hip_runtime.h>

// B=8, S=256, T=32, D=512, He=512, Fd=128
// flat row r = b*S+s for E/L1/F ([2048,512]); r = b*T+t for O/O2/O3 ([256,512])

typedef __attribute__((ext_vector_type(8))) short bf16x8;
typedef __attribute__((ext_vector_type(4))) float f32x4;

__device__ __forceinline__ unsigned short f2bf(float x) {
    union { float f; unsigned u; } v; v.f = x;
    unsigned r = v.u + 0x7fffu + ((v.u >> 16) & 1u);
    return (unsigned short)(r >> 16);
}

// ---- fused prep: blocks 0..1407 = fp32->bf16 cvt (E,Z,O); 1408..2239 = W transpose ----
__global__ __launch_bounds__(256) void prep_k(
    const float* __restrict__ E, const float* __restrict__ Z, const float* __restrict__ O,
    const float* __restrict__ W1, const float* __restrict__ W2,
    const float* __restrict__ W3, const float* __restrict__ W4,
    unsigned short* __restrict__ Ebf, unsigned short* __restrict__ Zbf,
    unsigned short* __restrict__ Obf,
    unsigned short* __restrict__ W1T, unsigned short* __restrict__ W2T,
    unsigned short* __restrict__ W3T, unsigned short* __restrict__ W4T)
{
    int bid = blockIdx.x;
    if (bid < 1408) {
        const float* src; unsigned short* dst; int base;
        if (bid < 1024)      { src = E; dst = Ebf; base = bid; }
        else if (bid < 1280) { src = Z; dst = Zbf; base = bid - 1024; }
        else                 { src = O; dst = Obf; base = bid - 1280; }
        int i = base * 1024 + threadIdx.x * 4;
        float4 v = *(const float4*)(src + i);
        ushort4 r;
        r.x = f2bf(v.x); r.y = f2bf(v.y); r.z = f2bf(v.z); r.w = f2bf(v.w);
        *(ushort4*)(dst + i) = r;
        return;
    }
    int tb = bid - 1408;
    const float* W; unsigned short* WT; int K;
    if (tb < 256)      {            W = W1; WT = W1T; K = 512; }
    else if (tb < 512) { tb -= 256; W = W2; WT = W2T; K = 512; }
    else if (tb < 576) { tb -= 512; W = W3; WT = W3T; K = 128; }
    else               { tb -= 576; W = W4; WT = W4T; K = 512; }
    int n0 = (tb & 15) * 32;
    int k0 = (tb >> 4) * 32;
    __shared__ float tile[32][33];
    int tx = threadIdx.x & 31, ty = threadIdx.x >> 5;  // 32 x 8
    #pragma unroll
    for (int i = 0; i < 32; i += 8)
        tile[ty + i][tx] = W[(k0 + ty + i) * 512 + n0 + tx];
    __syncthreads();
    #pragma unroll
    for (int i = 0; i < 32; i += 8)
        WT[(n0 + ty + i) * K + k0 + tx] = f2bf(tile[tx][ty + i]);
}

// ---- merged MFMA GEMM: C = tanh(A @ BT^T + bias), N=512, BK=64, packed 1D grid ----
// ids 0..255: L1 (M=2048,K=512) | 256..511: F (M=2048,K=128)
// 512..543: O2 (M=256,K=512)    | 544..575: O3 (M=256,K=512)
__global__ __launch_bounds__(256) void gemm_all_k(
    const unsigned short* __restrict__ Ebf, const unsigned short* __restrict__ Zbf,
    const unsigned short* __restrict__ Obf,
    const unsigned short* __restrict__ W1T, const unsigned short* __restrict__ W3T,
    const unsigned short* __restrict__ W2T, const unsigned short* __restrict__ W4T,
    const float* __restrict__ b1, const float* __restrict__ b3,
    const float* __restrict__ b2, const float* __restrict__ b4,
    float* __restrict__ L1, float* __restrict__ F,
    float* __restrict__ O2, float* __restrict__ O3)
{
    int id = blockIdx.x;
    const unsigned short* A; const unsigned short* BT; const float* bias; float* C;
    int K;
    if (id < 256)      {             A = Ebf; BT = W1T; bias = b1; C = L1; K = 512; }
    else if (id < 512) { id -= 256;  A = Zbf; BT = W3T; bias = b3; C = F;  K = 128; }
    else if (id < 544) { id -= 512;  A = Obf; BT = W2T; bias = b2; C = O2; K = 512; }
    else               { id -= 544;  A = Obf; BT = W4T; bias = b4; C = O3; K = 512; }
    int m0 = (id >> 3) * 64;
    int n0 = (id & 7) * 64;

    // stride 72 shorts (144B): 16B-aligned for b128, 2-way conflicts max (free)
    __shared__ unsigned short As[64 * 72];
    __shared__ unsigned short Bs[64 * 72];

    int tid  = threadIdx.x;
    int wave = tid >> 6;
    int lane = tid & 63;
    int lm   = lane & 15;
    int lq   = lane >> 4;

    int srow = tid >> 2;          // 0..63
    int scol = (tid & 3) * 16;    // 0,16,32,48 (shorts)

    f32x4 acc[4];
    #pragma unroll
    for (int c = 0; c < 4; ++c) acc[c] = f32x4{0.f, 0.f, 0.f, 0.f};

    for (int k0 = 0; k0 < K; k0 += 64) {
        __syncthreads();
        const unsigned short* Ap = &A[(m0 + srow) * K + k0 + scol];
        const unsigned short* Bp = &BT[(n0 + srow) * K + k0 + scol];
        *(uint4*)(&As[srow * 72 + scol])     = *(const uint4*)(Ap);
        *(uint4*)(&As[srow * 72 + scol + 8]) = *(const uint4*)(Ap + 8);
        *(uint4*)(&Bs[srow * 72 + scol])     = *(const uint4*)(Bp);
        *(uint4*)(&Bs[srow * 72 + scol + 8]) = *(const uint4*)(Bp + 8);
        __syncthreads();
        #pragma unroll
        for (int ks = 0; ks < 2; ++ks) {
            bf16x8 af = *(const bf16x8*)(&As[(wave * 16 + lm) * 72 + ks * 32 + lq * 8]);
            #pragma unroll
            for (int c = 0; c < 4; ++c) {
                bf16x8 bfr = *(const bf16x8*)(&Bs[(c * 16 + lm) * 72 + ks * 32 + lq * 8]);
                acc[c] = __builtin_amdgcn_mfma_f32_16x16x32_bf16(af, bfr, acc[c], 0, 0, 0);
            }
        }
    }

    // C/D layout: col = lane&15, row = (lane>>4)*4 + r  (verified round 1)
    #pragma unroll
    for (int c = 0; c < 4; ++c) {
        int col = n0 + c * 16 + lm;
        float bv = bias[col];
        #pragma unroll
        for (int r = 0; r < 4; ++r) {
            int row = m0 + wave * 16 + lq * 4 + r;
            float x = acc[c][r] + bv;
            x = fminf(fmaxf(x, -15.f), 15.f);
            float t = __expf(2.0f * x);
            C[row * 512 + col] = (t - 1.0f) / (t + 1.0f);
        }
    }
}

// ---- fused attention: one block per (b, d-chunk, t); single exp pass ----
// gamma = softmax_S(l1*c2 + f*c3) (alpha/beta denominators cancel).
// e[256] kept in registers (16 iters x f32x4, statically indexed).
// grid (8 b, 8 dc, 32 t) -> b fastest-varying = XCD pin; per-b slices L2-resident.
__global__ __launch_bounds__(256, 4) void attn_fused_k(
    const float* __restrict__ L1, const float* __restrict__ F,
    const float* __restrict__ O2, const float* __restrict__ O3,
    const float* __restrict__ Enc, const float* __restrict__ Out,
    float* __restrict__ out0, float* __restrict__ attn)
{
    int b  = blockIdx.x;
    int dc = blockIdx.y;                 // 0..7 -> 64 d each
    int t  = blockIdx.z;
    int bt = b * 32 + t;
    int dl = (threadIdx.x & 15) * 4;     // 0,4,...,60 within chunk
    int sr = threadIdx.x >> 4;           // 0..15
    int d0 = dc * 64;

    __shared__ float red_s[16 * 64];     // 4 KB
    __shared__ float red_c[16 * 64];     // 4 KB
    __shared__ float iv_lds[64];

    const float* L1b = L1  + (b * 256) * 512 + d0 + dl;
    const float* Fb  = F   + (b * 256) * 512 + d0 + dl;
    const float* Eb  = Enc + (b * 256) * 512 + d0 + dl;

    f32x4 c2 = *(const f32x4*)(O2 + bt * 512 + d0 + dl);
    f32x4 c3 = *(const f32x4*)(O3 + bt * 512 + d0 + dl);

    f32x4 e[16];
    f32x4 sum = f32x4{0.f, 0.f, 0.f, 0.f};
    f32x4 csum = f32x4{0.f, 0.f, 0.f, 0.f};

    #pragma unroll
    for (int i = 0; i < 16; ++i) {
        int s = i * 16 + sr;
        f32x4 l1 = *(const f32x4*)(L1b + s * 512);
        f32x4 f  = *(const f32x4*)(Fb  + s * 512);
        f32x4 eh = *(const f32x4*)(Eb  + s * 512);
        f32x4 ev;
        ev[0] = __expf(l1[0] * c2[0] + f[0] * c3[0]);
        ev[1] = __expf(l1[1] * c2[1] + f[1] * c3[1]);
        ev[2] = __expf(l1[2] * c2[2] + f[2] * c3[2]);
        ev[3] = __expf(l1[3] * c2[3] + f[3] * c3[3]);
        e[i] = ev;
        sum[0] += ev[0]; sum[1] += ev[1]; sum[2] += ev[2]; sum[3] += ev[3];
        csum[0] += ev[0] * eh[0]; csum[1] += ev[1] * eh[1];
        csum[2] += ev[2] * eh[2]; csum[3] += ev[3] * eh[3];
    }

    *(f32x4*)(&red_s[sr * 64 + dl]) = sum;
    *(f32x4*)(&red_c[sr * 64 + dl]) = csum;
    __syncthreads();

    if (threadIdx.x < 64) {
        int d = threadIdx.x;
        float s_ = 0.f, c_ = 0.f;
        #pragma unroll
        for (int r = 0; r < 16; ++r) {
            s_ += red_s[r * 64 + d];
            c_ += red_c[r * 64 + d];
        }
        float inv = 1.0f / s_;
        iv_lds[d] = inv;
        out0[bt * 1024 + 512 + d0 + d] = c_ * inv;        // contex
        out0[bt * 1024 + d0 + d]       = Out[bt * 512 + d0 + d];  // concat copy
    }
    __syncthreads();

    f32x4 iv = *(const f32x4*)(&iv_lds[dl]);
    float* ab = attn + ((size_t)bt * 256) * 512 + d0 + dl;
    #pragma unroll
    for (int i = 0; i < 16; ++i) {
        int s = i * 16 + sr;
        f32x4 g;
        g[0] = e[i][0] * iv[0];
        g[1] = e[i][1] * iv[1];
        g[2] = e[i][2] * iv[2];
        g[3] = e[i][3] * iv[3];
        __builtin_nontemporal_store(g, (f32x4*)(ab + (size_t)s * 512));
    }
}

extern "C" void kernel_launch(void* const* d_in, const int* in_sizes, int n_in,
                              void* d_out, int out_size, void* d_ws, size_t ws_size,
                              hipStream_t stream)
{
    const float* Out = (const float*)d_in[0];
    const float* Enc = (const float*)d_in[1];
    const float* Z   = (const float*)d_in[2];
    const float* W1  = (const float*)d_in[3];
    const float* b1  = (const float*)d_in[4];
    const float* W2  = (const float*)d_in[5];
    const float* b2  = (const float*)d_in[6];
    const float* W3  = (const float*)d_in[7];
    const float* b3  = (const float*)d_in[8];
    const float* W4  = (const float*)d_in[9];
    const float* b4  = (const float*)d_in[10];

    char* ws = (char*)d_ws;
    size_t off = 0;
    auto alloc = [&](size_t n) -> char* {
        char* p = ws + off; off += (n + 255) & ~(size_t)255; return p;
    };
    unsigned short* Ebf = (unsigned short*)alloc(1048576 * 2);
    unsigned short* Zbf = (unsigned short*)alloc(262144 * 2);
    unsigned short* Obf = (unsigned short*)alloc(131072 * 2);
    unsigned short* W1T = (unsigned short*)alloc(262144 * 2);
    unsigned short* W2T = (unsigned short*)alloc(262144 * 2);
    unsigned short* W3T = (unsigned short*)alloc(65536 * 2);
    unsigned short* W4T = (unsigned short*)alloc(262144 * 2);
    float* L1 = (float*)alloc(1048576 * 4);
    float* F  = (float*)alloc(1048576 * 4);
    float* O2 = (float*)alloc(131072 * 4);
    float* O3 = (float*)alloc(131072 * 4);

    float* out0 = (float*)d_out;            // [8,32,1024]
    float* attn = out0 + 262144;            // [8,32,256,512]

    hipLaunchKernelGGL(prep_k, dim3(2240), dim3(256), 0, stream,
                       Enc, Z, Out, W1, W2, W3, W4,
                       Ebf, Zbf, Obf, W1T, W2T, W3T, W4T);
    hipLaunchKernelGGL(gemm_all_k, dim3(576), dim3(256), 0, stream,
                       Ebf, Zbf, Obf, W1T, W3T, W2T, W4T,
                       b1, b3, b2, b4, L1, F, O2, O3);
    hipLaunchKernelGGL(attn_fused_k, dim3(8, 8, 32), dim3(256), 0, stream,
                       L1, F, O2, O3, Enc, Out, out0, attn);
}